// Round 3
// baseline (10631.004 us; speedup 1.0000x reference)
//
#include <hip/hip_runtime.h>

// InputAttnEncoder round 3: weights resident in VGPRs.
// 32 blocks x 16 rows x 16 waves. Wave specialization:
//   waves 0-3 : attn1 tiles 4w..4w+3          (80 chunks in regs)
//   waves 4-7 : attn2 tiles 2p,2p+1 (18) ; wave 4 also attn1 tile16 (+20)
//   waves 8-15: 8 gate tiles (i,f,g,o quadruples) = Whh 64 + Wih 32 chunks
// Gates, c-state and LSTM pointwise stay in registers (no s_g/s_c LDS).
// 3 barriers/step. Per-step weight memory traffic: ZERO.

#define Bb 512
#define Tt 256
#define Ff 128
#define Hh 256

typedef unsigned short ushort_t;
typedef short s16x8 __attribute__((ext_vector_type(8)));
typedef float f32x4 __attribute__((ext_vector_type(4)));

// prepack geometry (chunk = 64 lanes x 16B) — identical to round 2
#define A1_NK 20
#define A2_NK 9
#define IH_NK 4
#define HH_NK 8
#define CH_A1 0
#define CH_A2 21760            // + 17*20*64
#define CH_IH 26368            // + 8*9*64
#define CH_HH 42752            // + 64*4*64
#define CH_TOTAL 75520         // + 64*8*64

// LDS pitches (ushort elements); all give <=2-way bank aliasing (free)
#define ZP 648    // z row: [x 0..127 | h 128..383 | c 384..639]
#define AP 296    // attn score row, K padded 257->288 (pads zero)
#define XIP 136   // xi row, K=128

__device__ inline ushort_t f2b(float f) {
    unsigned u = __float_as_uint(f);
    unsigned r = (u + 0x7fffu + ((u >> 16) & 1u)) >> 16;  // RNE
    return (ushort_t)r;
}
__device__ inline float b2f(ushort_t u) {
    return __uint_as_float(((unsigned)u) << 16);
}
__device__ inline float fast_sig(float x) { return 1.f / (1.f + __expf(-x)); }
__device__ inline float fast_tanh(float x) {
    float cx = fminf(fmaxf(x, -15.f), 15.f);
    float e = __expf(2.f * cx);
    return (e - 1.f) / (e + 1.f);
}

__global__ void conv_kernel(const float* __restrict__ a1,  // [257][640]
                            const float* __restrict__ a2,  // [128][257]
                            const float* __restrict__ ih,  // [1024][128]
                            const float* __restrict__ hh,  // [1024][256]
                            ushort_t* __restrict__ ws) {
    int idx = blockIdx.x * 256 + threadIdx.x;
    if (idx >= CH_TOTAL) return;
    int lane = idx & 63;
    int jo = lane & 15;
    int ko = (lane >> 4) * 8;
    float v[8];
    if (idx < CH_A2) {
        int cix = idx >> 6;
        int tile = cix / A1_NK, kc = cix % A1_NK;
        int j = tile * 16 + jo, k = kc * 32 + ko;
        #pragma unroll
        for (int e = 0; e < 8; ++e) v[e] = (j < 257) ? a1[j * 640 + k + e] : 0.f;
    } else if (idx < CH_IH) {
        int cix = (idx - CH_A2) >> 6;
        int tile = cix / A2_NK, kc = cix % A2_NK;
        int j = tile * 16 + jo, k = kc * 32 + ko;
        #pragma unroll
        for (int e = 0; e < 8; ++e) v[e] = (k + e < 257) ? a2[j * 257 + k + e] : 0.f;
    } else if (idx < CH_HH) {
        int cix = (idx - CH_IH) >> 6;
        int tile = cix / IH_NK, kc = cix % IH_NK;
        int j = tile * 16 + jo, k = kc * 32 + ko;
        #pragma unroll
        for (int e = 0; e < 8; ++e) v[e] = ih[j * 128 + k + e];
    } else {
        int cix = (idx - CH_HH) >> 6;
        int tile = cix / HH_NK, kc = cix % HH_NK;
        int j = tile * 16 + jo, k = kc * 32 + ko;
        #pragma unroll
        for (int e = 0; e < 8; ++e) v[e] = hh[j * 256 + k + e];
    }
    union { s16x8 v8; ushort_t u[8]; } o;
    #pragma unroll
    for (int e = 0; e < 8; ++e) o.u[e] = f2b(v[e]);
    ((s16x8*)ws)[idx] = o.v8;
}

__global__ __launch_bounds__(1024) void lstm_mfma(
    const float* __restrict__ X,    // [512][256][128]
    const float* __restrict__ b1,   // [257]
    const float* __restrict__ b2,   // [128]
    const float* __restrict__ bih,  // [1024]
    const float* __restrict__ bhh,  // [1024]
    const ushort_t* __restrict__ wsw,
    float* __restrict__ out)        // hs [512][256][256] then cs
{
    __shared__ ushort_t z_bf[16][ZP];
    __shared__ ushort_t a_bf[16][AP];
    __shared__ ushort_t xi_bf[16][XIP];

    const int tid = threadIdx.x;
    const int w   = tid >> 6;
    const int l   = tid & 63;
    const int lj  = l & 15;
    const int lr4 = (l >> 4) * 4;
    const int lk8 = (l >> 4) * 8;
    const int b0  = blockIdx.x * 16;

    const s16x8* __restrict__ W8 = (const s16x8*)wsw;

    // ---------------- weight preload into registers ----------------
    s16x8 wreg[96];
    float bA1[4] = {0.f, 0.f, 0.f, 0.f};
    float b1_256 = 0.f;
    float bA2[2] = {0.f, 0.f};
    float bgq[8];
    #pragma unroll
    for (int u = 0; u < 8; ++u) bgq[u] = 0.f;

    if (w < 4) {
        #pragma unroll
        for (int t2 = 0; t2 < 4; ++t2) {
            #pragma unroll
            for (int kc = 0; kc < A1_NK; ++kc)
                wreg[t2 * A1_NK + kc] = W8[CH_A1 + ((4 * w + t2) * A1_NK + kc) * 64 + l];
            bA1[t2] = b1[64 * w + 16 * t2 + lj];
        }
    } else if (w < 8) {
        int p = w - 4;
        #pragma unroll
        for (int t2 = 0; t2 < 2; ++t2) {
            #pragma unroll
            for (int kc = 0; kc < A2_NK; ++kc)
                wreg[t2 * A2_NK + kc] = W8[CH_A2 + ((2 * p + t2) * A2_NK + kc) * 64 + l];
            bA2[t2] = b2[32 * p + 16 * t2 + lj];
        }
        if (w == 4) {
            #pragma unroll
            for (int kc = 0; kc < A1_NK; ++kc)
                wreg[18 + kc] = W8[CH_A1 + (16 * A1_NK + kc) * 64 + l];
            b1_256 = b1[256];
        }
    } else {
        int g = w - 8;
        #pragma unroll
        for (int q = 0; q < 2; ++q) {
            #pragma unroll
            for (int i = 0; i < 4; ++i) {
                int n = i * 16 + q * 8 + g;      // gate tile (16 cols)
                int u = q * 4 + i;
                #pragma unroll
                for (int kc = 0; kc < HH_NK; ++kc)
                    wreg[u * 8 + kc] = W8[CH_HH + (n * HH_NK + kc) * 64 + l];
                #pragma unroll
                for (int kc = 0; kc < IH_NK; ++kc)
                    wreg[64 + u * 4 + kc] = W8[CH_IH + (n * IH_NK + kc) * 64 + l];
                int j = 256 * i + 128 * q + 16 * g + lj;
                bgq[u] = bih[j] + bhh[j];
            }
        }
    }

    f32x4 agate[8];
    float c_reg[8];
    #pragma unroll
    for (int u = 0; u < 8; ++u) c_reg[u] = 0.f;

    // ---------------- LDS init ----------------
    // h,c regions zero: 16 rows x 512 = 1024 chunks of 8
    {
        int i = tid;
        int r = i >> 6, c = (i & 63) * 8;
        s16x8 zz = {0, 0, 0, 0, 0, 0, 0, 0};
        *(s16x8*)&z_bf[r][128 + c] = zz;
    }
    if (tid < 592) {  // a_bf zero (incl pads): 16*296/8
        int r = tid / 37, c = (tid - r * 37) * 8;
        s16x8 zz = {0, 0, 0, 0, 0, 0, 0, 0};
        *(s16x8*)&a_bf[r][c] = zz;
    }
    if (tid < 256) {  // x_0
        int r = tid >> 4, c = (tid & 15) * 8;
        float4 x0 = *(const float4*)&X[((size_t)(b0 + r) * Tt) * Ff + c];
        float4 x1 = *(const float4*)&X[((size_t)(b0 + r) * Tt) * Ff + c + 4];
        s16x8 v;
        v[0] = (short)f2b(x0.x); v[1] = (short)f2b(x0.y);
        v[2] = (short)f2b(x0.z); v[3] = (short)f2b(x0.w);
        v[4] = (short)f2b(x1.x); v[5] = (short)f2b(x1.y);
        v[6] = (short)f2b(x1.z); v[7] = (short)f2b(x1.w);
        *(s16x8*)&z_bf[r][c] = v;
    }
    __syncthreads();

    float* __restrict__ hs = out;
    float* __restrict__ cs = out + (size_t)Bb * Tt * Hh;

    float4 xp0, xp1;

    for (int t = 0; t < Tt; ++t) {
        // ================= Phase A =================
        if (w < 4) {
            // attn1: 4 tiles, K=640 (kc outer, tiles inner -> dep distance 4)
            f32x4 acc[4];
            #pragma unroll
            for (int t2 = 0; t2 < 4; ++t2) acc[t2] = (f32x4){0.f, 0.f, 0.f, 0.f};
            #pragma unroll
            for (int kc = 0; kc < A1_NK; ++kc) {
                s16x8 a = *(const s16x8*)&z_bf[lj][kc * 32 + lk8];
                #pragma unroll
                for (int t2 = 0; t2 < 4; ++t2)
                    acc[t2] = __builtin_amdgcn_mfma_f32_16x16x32_bf16(a, wreg[t2 * A1_NK + kc], acc[t2], 0, 0, 0);
            }
            #pragma unroll
            for (int t2 = 0; t2 < 4; ++t2) {
                int j = 64 * w + 16 * t2 + lj;
                #pragma unroll
                for (int q = 0; q < 4; ++q)
                    a_bf[lr4 + q][j] = f2b(fast_tanh(acc[t2][q] + bA1[t2]));
            }
        } else if (w == 4) {
            // attn1 tile 16 (only j=256 valid)
            f32x4 acc = {0.f, 0.f, 0.f, 0.f};
            #pragma unroll
            for (int kc = 0; kc < A1_NK; ++kc) {
                s16x8 a = *(const s16x8*)&z_bf[lj][kc * 32 + lk8];
                acc = __builtin_amdgcn_mfma_f32_16x16x32_bf16(a, wreg[18 + kc], acc, 0, 0, 0);
            }
            if (lj == 0) {
                #pragma unroll
                for (int q = 0; q < 4; ++q)
                    a_bf[lr4 + q][256] = f2b(fast_tanh(acc[q] + b1_256));
            }
        } else if (w >= 8) {
            // Whh into agate (init with gate bias)
            #pragma unroll
            for (int u = 0; u < 8; ++u)
                agate[u] = (f32x4){bgq[u], bgq[u], bgq[u], bgq[u]};
            #pragma unroll
            for (int kc = 0; kc < HH_NK; ++kc) {
                s16x8 a = *(const s16x8*)&z_bf[lj][128 + kc * 32 + lk8];
                #pragma unroll
                for (int u = 0; u < 8; ++u)
                    agate[u] = __builtin_amdgcn_mfma_f32_16x16x32_bf16(a, wreg[u * 8 + kc], agate[u], 0, 0, 0);
            }
        }
        __syncthreads();  // ---- a_bf ready ----

        // ================= Phase B =================
        if (w < 4) {
            if (t + 1 < Tt) {   // issue x_{t+1} loads (consumed in phase C)
                const float* xs = &X[((size_t)(b0 + (tid >> 4)) * Tt + (t + 1)) * Ff + (tid & 15) * 8];
                xp0 = *(const float4*)xs;
                xp1 = *(const float4*)(xs + 4);
            }
        } else if (w < 8) {
            // attn2: 2 tiles, K=288 (includes j=256 col + zero pads)
            f32x4 acc[2];
            acc[0] = (f32x4){0.f, 0.f, 0.f, 0.f};
            acc[1] = (f32x4){0.f, 0.f, 0.f, 0.f};
            #pragma unroll
            for (int kc = 0; kc < A2_NK; ++kc) {
                s16x8 a = *(const s16x8*)&a_bf[lj][kc * 32 + lk8];
                #pragma unroll
                for (int t2 = 0; t2 < 2; ++t2)
                    acc[t2] = __builtin_amdgcn_mfma_f32_16x16x32_bf16(a, wreg[t2 * A2_NK + kc], acc[t2], 0, 0, 0);
            }
            #pragma unroll
            for (int t2 = 0; t2 < 2; ++t2) {
                int j = 32 * (w - 4) + 16 * t2 + lj;
                #pragma unroll
                for (int q = 0; q < 4; ++q) {
                    int r = lr4 + q;
                    float xf = b2f(z_bf[r][j]);          // x_t (bf16)
                    float xi = (acc[t2][q] + bA2[t2]) * xf;
                    xi_bf[r][j] = f2b(xi);
                }
            }
        }
        __syncthreads();  // ---- xi ready; x_t no longer needed ----

        // ================= Phase C + D =================
        if (w >= 8) {
            // Wih accumulate onto agate (registers)
            #pragma unroll
            for (int kc = 0; kc < IH_NK; ++kc) {
                s16x8 a = *(const s16x8*)&xi_bf[lj][kc * 32 + lk8];
                #pragma unroll
                for (int u = 0; u < 8; ++u)
                    agate[u] = __builtin_amdgcn_mfma_f32_16x16x32_bf16(a, wreg[64 + u * 4 + kc], agate[u], 0, 0, 0);
            }
            // pointwise LSTM, all in registers
            int g = w - 8;
            #pragma unroll
            for (int q = 0; q < 2; ++q) {
                int d = 128 * q + 16 * g + lj;
                #pragma unroll
                for (int qq = 0; qq < 4; ++qq) {
                    int r = lr4 + qq;
                    float gi = agate[q * 4 + 0][qq];
                    float gf = agate[q * 4 + 1][qq];
                    float gg = agate[q * 4 + 2][qq];
                    float go = agate[q * 4 + 3][qq];
                    float ig = fast_sig(gi);
                    float fg = fast_sig(gf);
                    float g_g = fast_tanh(gg);
                    float og = fast_sig(go);
                    float cn = fmaf(fg, c_reg[q * 4 + qq], ig * g_g);
                    float hn = og * fast_tanh(cn);
                    c_reg[q * 4 + qq] = cn;
                    z_bf[r][128 + d] = f2b(hn);
                    z_bf[r][384 + d] = f2b(cn);
                    size_t oi = ((size_t)(b0 + r) * Tt + t) * Hh + d;
                    hs[oi] = hn;
                    cs[oi] = cn;
                }
            }
        } else if (w < 4) {
            if (t + 1 < Tt) {   // write x_{t+1} into z (x region free after phase B)
                int r = tid >> 4, c = (tid & 15) * 8;
                s16x8 v;
                v[0] = (short)f2b(xp0.x); v[1] = (short)f2b(xp0.y);
                v[2] = (short)f2b(xp0.z); v[3] = (short)f2b(xp0.w);
                v[4] = (short)f2b(xp1.x); v[5] = (short)f2b(xp1.y);
                v[6] = (short)f2b(xp1.z); v[7] = (short)f2b(xp1.w);
                *(s16x8*)&z_bf[r][c] = v;
            }
        }
        __syncthreads();  // ---- h,c,x for step t+1 ready ----
    }
}

extern "C" void kernel_launch(void* const* d_in, const int* in_sizes, int n_in,
                              void* d_out, int out_size, void* d_ws, size_t ws_size,
                              hipStream_t stream) {
    const float* X   = (const float*)d_in[0];
    const float* a1W = (const float*)d_in[1];
    const float* a1b = (const float*)d_in[2];
    const float* a2W = (const float*)d_in[3];
    const float* a2b = (const float*)d_in[4];
    const float* Wih = (const float*)d_in[5];
    const float* Whh = (const float*)d_in[6];
    const float* bih = (const float*)d_in[7];
    const float* bhh = (const float*)d_in[8];
    ushort_t* ws = (ushort_t*)d_ws;

    hipLaunchKernelGGL(conv_kernel, dim3(CH_TOTAL / 256), dim3(256), 0, stream,
                       a1W, a2W, Wih, Whh, ws);
    hipLaunchKernelGGL(lstm_mfma, dim3(32), dim3(1024), 0, stream,
                       X, a1b, a2b, bih, bhh, ws, (float*)d_out);
}

// Round 4
// 7479.624 us; speedup vs baseline: 1.4213x; 1.4213x over previous
//
#include <hip/hip_runtime.h>

// InputAttnEncoder round 4: 32 blocks x 512 threads (8 waves, 2/SIMD -> 256 VGPR cap).
// Wih (256 chunks) pinned in VGPRs (32/wave, statically indexed).
// attn2 (72 chunks) pinned in LDS. A1 + Whh (852 KB/step) streamed from L2 with
// software-pipelined register double-buffers. Gates + c state in registers.

#define Bb 512
#define Tt 256
#define Ff 128
#define Hh 256

typedef unsigned short ushort_t;
typedef short s16x8 __attribute__((ext_vector_type(8)));
typedef float f32x4 __attribute__((ext_vector_type(4)));

#define A1_NK 20
#define A2_NK 9
#define IH_NK 4
#define HH_NK 8
#define CH_A1 0
#define CH_A2 21760
#define CH_IH 26368
#define CH_HH 42752
#define CH_TOTAL 75520

#define ZP 648    // z row pitch (ushort): [x 0..127 | h 128..383 | c 384..639]
#define AP 296    // attn score row pitch (K padded 257->288, pads zero)
#define XIP 136   // xi row pitch

__device__ inline ushort_t f2b(float f) {
    unsigned u = __float_as_uint(f);
    unsigned r = (u + 0x7fffu + ((u >> 16) & 1u)) >> 16;  // RNE
    return (ushort_t)r;
}
__device__ inline float b2f(ushort_t u) {
    return __uint_as_float(((unsigned)u) << 16);
}
__device__ inline float fast_sig(float x) { return 1.f / (1.f + __expf(-x)); }
__device__ inline float fast_tanh(float x) {
    float cx = fminf(fmaxf(x, -15.f), 15.f);
    float e = __expf(2.f * cx);
    return (e - 1.f) / (e + 1.f);
}

__global__ void conv_kernel(const float* __restrict__ a1,  // [257][640]
                            const float* __restrict__ a2,  // [128][257]
                            const float* __restrict__ ih,  // [1024][128]
                            const float* __restrict__ hh,  // [1024][256]
                            ushort_t* __restrict__ ws) {
    int idx = blockIdx.x * 256 + threadIdx.x;
    if (idx >= CH_TOTAL) return;
    int lane = idx & 63;
    int jo = lane & 15;
    int ko = (lane >> 4) * 8;
    float v[8];
    if (idx < CH_A2) {
        int cix = idx >> 6;
        int tile = cix / A1_NK, kc = cix % A1_NK;
        int j = tile * 16 + jo, k = kc * 32 + ko;
        #pragma unroll
        for (int e = 0; e < 8; ++e) v[e] = (j < 257) ? a1[j * 640 + k + e] : 0.f;
    } else if (idx < CH_IH) {
        int cix = (idx - CH_A2) >> 6;
        int tile = cix / A2_NK, kc = cix % A2_NK;
        int j = tile * 16 + jo, k = kc * 32 + ko;
        #pragma unroll
        for (int e = 0; e < 8; ++e) v[e] = (k + e < 257) ? a2[j * 257 + k + e] : 0.f;
    } else if (idx < CH_HH) {
        int cix = (idx - CH_IH) >> 6;
        int tile = cix / IH_NK, kc = cix % IH_NK;
        int j = tile * 16 + jo, k = kc * 32 + ko;
        #pragma unroll
        for (int e = 0; e < 8; ++e) v[e] = ih[j * 128 + k + e];
    } else {
        int cix = (idx - CH_HH) >> 6;
        int tile = cix / HH_NK, kc = cix % HH_NK;
        int j = tile * 16 + jo, k = kc * 32 + ko;
        #pragma unroll
        for (int e = 0; e < 8; ++e) v[e] = hh[j * 256 + k + e];
    }
    union { s16x8 v8; ushort_t u[8]; } o;
    #pragma unroll
    for (int e = 0; e < 8; ++e) o.u[e] = f2b(v[e]);
    ((s16x8*)ws)[idx] = o.v8;
}

__global__ __launch_bounds__(512) void lstm_mfma(
    const float* __restrict__ X,    // [512][256][128]
    const float* __restrict__ b1,   // [257]
    const float* __restrict__ b2,   // [128]
    const float* __restrict__ bih,  // [1024]
    const float* __restrict__ bhh,  // [1024]
    const ushort_t* __restrict__ wsw,
    float* __restrict__ out)        // hs [512][256][256] then cs
{
    __shared__ s16x8    a2w[8 * A2_NK * 64];   // 73,728 B: attn2 weights pinned
    __shared__ ushort_t z_bf[16][ZP];          // 20,736 B
    __shared__ ushort_t a_bf[16][AP];          //  9,472 B
    __shared__ ushort_t xi_bf[16][XIP];        //  4,352 B

    const int tid = threadIdx.x;
    const int w   = tid >> 6;       // wave 0..7
    const int l   = tid & 63;
    const int lj  = l & 15;
    const int lr4 = (l >> 4) * 4;
    const int lk8 = (l >> 4) * 8;
    const int b0  = blockIdx.x * 16;

    const s16x8* __restrict__ W8 = (const s16x8*)wsw;

    // ---------------- pinned weights: Wih in VGPRs (32 chunks = 128 VGPR) ----------------
    s16x8 w_ih[32];
    float bgq[8];
    #pragma unroll
    for (int u = 0; u < 8; ++u) {
        int n = (u & 3) * 16 + (u >> 2) * 8 + w;   // gate tile
        #pragma unroll
        for (int kc = 0; kc < IH_NK; ++kc)
            w_ih[u * 4 + kc] = W8[CH_IH + (n * IH_NK + kc) * 64 + l];
        int j = n * 16 + lj;
        bgq[u] = bih[j] + bhh[j];
    }

    // ---------------- pinned weights: attn2 into LDS ----------------
    for (int i = tid; i < 8 * A2_NK * 64; i += 512) a2w[i] = W8[CH_A2 + i];

    // ---------------- biases ----------------
    float bA1_0 = b1[16 * w + lj];
    float bA1_1 = b1[128 + 16 * w + lj];
    float b1_256 = (w == 0) ? b1[256] : 0.f;
    float bA2 = b2[16 * w + lj];

    f32x4 agate[8];
    float c_reg[8];
    #pragma unroll
    for (int u = 0; u < 8; ++u) c_reg[u] = 0.f;

    // ---------------- LDS init ----------------
    {   // h,c = 0 (bf16): 16 rows x 512 = 1024 chunks of 8 ushorts
        s16x8 zz = {0, 0, 0, 0, 0, 0, 0, 0};
        #pragma unroll
        for (int rep = 0; rep < 2; ++rep) {
            int i = tid + rep * 512;
            int r = i >> 6, c = (i & 63) * 8;
            *(s16x8*)&z_bf[r][128 + c] = zz;
        }
        for (int i = tid; i < 592; i += 512) {   // a_bf incl pads
            int r = i / 37, c = (i - r * 37) * 8;
            *(s16x8*)&a_bf[r][c] = zz;
        }
    }
    if (tid < 256) {  // x_0
        int r = tid >> 4, c = (tid & 15) * 8;
        float4 x0 = *(const float4*)&X[((size_t)(b0 + r) * Tt) * Ff + c];
        float4 x1 = *(const float4*)&X[((size_t)(b0 + r) * Tt) * Ff + c + 4];
        s16x8 v;
        v[0] = (short)f2b(x0.x); v[1] = (short)f2b(x0.y);
        v[2] = (short)f2b(x0.z); v[3] = (short)f2b(x0.w);
        v[4] = (short)f2b(x1.x); v[5] = (short)f2b(x1.y);
        v[6] = (short)f2b(x1.z); v[7] = (short)f2b(x1.w);
        *(s16x8*)&z_bf[r][c] = v;
    }
    __syncthreads();

    float* __restrict__ hs = out;
    float* __restrict__ cs = out + (size_t)Bb * Tt * Hh;

    float4 xp0, xp1;

    for (int t = 0; t < Tt; ++t) {
        // ===== Phase A: attn1, streamed (tiles w and 8+w; wave 0 also tile 16) =====
        {
            const s16x8* Wa = W8 + CH_A1;
            s16x8 bufA[5][2];
            #pragma unroll
            for (int kc = 0; kc < 4; ++kc) {
                bufA[kc][0] = Wa[(w * A1_NK + kc) * 64 + l];
                bufA[kc][1] = Wa[((8 + w) * A1_NK + kc) * 64 + l];
            }
            f32x4 acc0 = {0.f, 0.f, 0.f, 0.f};
            f32x4 acc1 = {0.f, 0.f, 0.f, 0.f};
            #pragma unroll
            for (int kc = 0; kc < A1_NK; ++kc) {
                if (kc + 4 < A1_NK) {
                    bufA[(kc + 4) % 5][0] = Wa[(w * A1_NK + kc + 4) * 64 + l];
                    bufA[(kc + 4) % 5][1] = Wa[((8 + w) * A1_NK + kc + 4) * 64 + l];
                }
                s16x8 a = *(const s16x8*)&z_bf[lj][kc * 32 + lk8];
                acc0 = __builtin_amdgcn_mfma_f32_16x16x32_bf16(a, bufA[kc % 5][0], acc0, 0, 0, 0);
                acc1 = __builtin_amdgcn_mfma_f32_16x16x32_bf16(a, bufA[kc % 5][1], acc1, 0, 0, 0);
            }
            int j0 = 16 * w + lj;
            #pragma unroll
            for (int q = 0; q < 4; ++q) {
                a_bf[lr4 + q][j0]       = f2b(fast_tanh(acc0[q] + bA1_0));
                a_bf[lr4 + q][128 + j0] = f2b(fast_tanh(acc1[q] + bA1_1));
            }
        }
        if (w == 0) {  // attn1 tile 16 (only j=256 valid)
            const s16x8* Wa = W8 + CH_A1 + 16 * A1_NK * 64;
            s16x8 buf16[4];
            #pragma unroll
            for (int kc = 0; kc < 3; ++kc) buf16[kc] = Wa[kc * 64 + l];
            f32x4 acc2 = {0.f, 0.f, 0.f, 0.f};
            #pragma unroll
            for (int kc = 0; kc < A1_NK; ++kc) {
                if (kc + 3 < A1_NK) buf16[(kc + 3) & 3] = Wa[(kc + 3) * 64 + l];
                s16x8 a = *(const s16x8*)&z_bf[lj][kc * 32 + lk8];
                acc2 = __builtin_amdgcn_mfma_f32_16x16x32_bf16(a, buf16[kc & 3], acc2, 0, 0, 0);
            }
            if (lj == 0) {
                #pragma unroll
                for (int q = 0; q < 4; ++q)
                    a_bf[lr4 + q][256] = f2b(fast_tanh(acc2[q] + b1_256));
            }
        }
        __syncthreads();  // ---- a_bf ready ----

        // ===== Phase B: x prefetch + Whh (streamed) + attn2 (LDS) =====
        if (tid < 256 && t + 1 < Tt) {
            const float* xs = &X[((size_t)(b0 + (tid >> 4)) * Tt + (t + 1)) * Ff + (tid & 15) * 8];
            xp0 = *(const float4*)xs;
            xp1 = *(const float4*)(xs + 4);
        }
        {
            // Whh: kc outer (8), tiles inner (8, in halves of 4), dbuf by half-group
            s16x8 bufH[2][4];
            #pragma unroll
            for (int j2 = 0; j2 < 4; ++j2) {
                int n = (j2 & 3) * 16 + 0 * 8 + w;            // u = j2 (q=0,i=j2)
                bufH[0][j2] = W8[CH_HH + (n * HH_NK + 0) * 64 + l];
            }
            #pragma unroll
            for (int u = 0; u < 8; ++u)
                agate[u] = (f32x4){bgq[u], bgq[u], bgq[u], bgq[u]};

            // attn2 (LDS-pinned B) — runs while first Whh group is in flight
            {
                f32x4 acc = {0.f, 0.f, 0.f, 0.f};
                #pragma unroll
                for (int kc = 0; kc < A2_NK; ++kc) {
                    s16x8 a = *(const s16x8*)&a_bf[lj][kc * 32 + lk8];
                    s16x8 b = a2w[(w * A2_NK + kc) * 64 + l];
                    acc = __builtin_amdgcn_mfma_f32_16x16x32_bf16(a, b, acc, 0, 0, 0);
                }
                int j = 16 * w + lj;
                #pragma unroll
                for (int q = 0; q < 4; ++q) {
                    int r = lr4 + q;
                    float xi = (acc[q] + bA2) * b2f(z_bf[r][j]);
                    xi_bf[r][j] = f2b(xi);
                }
            }

            // Whh main: 16 groups of 4 chunks (g = kc*2 + half)
            s16x8 ah;
            #pragma unroll
            for (int g = 0; g < 16; ++g) {
                const int kc = g >> 1, half = g & 1;
                if (g + 1 < 16) {
                    const int kn = (g + 1) >> 1, hn = (g + 1) & 1;
                    #pragma unroll
                    for (int j2 = 0; j2 < 4; ++j2) {
                        int u = hn * 4 + j2;
                        int n = (u & 3) * 16 + (u >> 2) * 8 + w;
                        bufH[(g + 1) & 1][j2] = W8[CH_HH + (n * HH_NK + kn) * 64 + l];
                    }
                }
                if (half == 0)
                    ah = *(const s16x8*)&z_bf[lj][128 + kc * 32 + lk8];
                #pragma unroll
                for (int j2 = 0; j2 < 4; ++j2) {
                    int u = half * 4 + j2;
                    agate[u] = __builtin_amdgcn_mfma_f32_16x16x32_bf16(ah, bufH[g & 1][j2], agate[u], 0, 0, 0);
                }
            }
        }
        __syncthreads();  // ---- xi ready ----

        // ===== Phase C: Wih (pinned) + pointwise + state/output writes =====
        {
            #pragma unroll
            for (int kc = 0; kc < IH_NK; ++kc) {
                s16x8 a = *(const s16x8*)&xi_bf[lj][kc * 32 + lk8];
                #pragma unroll
                for (int u = 0; u < 8; ++u)
                    agate[u] = __builtin_amdgcn_mfma_f32_16x16x32_bf16(a, w_ih[u * 4 + kc], agate[u], 0, 0, 0);
            }
            #pragma unroll
            for (int q = 0; q < 2; ++q) {
                int d = 128 * q + 16 * w + lj;
                #pragma unroll
                for (int qq = 0; qq < 4; ++qq) {
                    int r = lr4 + qq;
                    float gi = agate[q * 4 + 0][qq];
                    float gf = agate[q * 4 + 1][qq];
                    float gg = agate[q * 4 + 2][qq];
                    float go = agate[q * 4 + 3][qq];
                    float ig = fast_sig(gi);
                    float fg = fast_sig(gf);
                    float g_g = fast_tanh(gg);
                    float og = fast_sig(go);
                    float cn = fmaf(fg, c_reg[q * 4 + qq], ig * g_g);
                    float hn = og * fast_tanh(cn);
                    c_reg[q * 4 + qq] = cn;
                    z_bf[r][128 + d] = f2b(hn);
                    z_bf[r][384 + d] = f2b(cn);
                    size_t oi = ((size_t)(b0 + r) * Tt + t) * Hh + d;
                    hs[oi] = hn;
                    cs[oi] = cn;
                }
            }
        }
        if (tid < 256 && t + 1 < Tt) {  // write x_{t+1}
            int r = tid >> 4, c = (tid & 15) * 8;
            s16x8 v;
            v[0] = (short)f2b(xp0.x); v[1] = (short)f2b(xp0.y);
            v[2] = (short)f2b(xp0.z); v[3] = (short)f2b(xp0.w);
            v[4] = (short)f2b(xp1.x); v[5] = (short)f2b(xp1.y);
            v[6] = (short)f2b(xp1.z); v[7] = (short)f2b(xp1.w);
            *(s16x8*)&z_bf[r][c] = v;
        }
        __syncthreads();  // ---- state for t+1 ready ----
    }
}

extern "C" void kernel_launch(void* const* d_in, const int* in_sizes, int n_in,
                              void* d_out, int out_size, void* d_ws, size_t ws_size,
                              hipStream_t stream) {
    const float* X   = (const float*)d_in[0];
    const float* a1W = (const float*)d_in[1];
    const float* a1b = (const float*)d_in[2];
    const float* a2W = (const float*)d_in[3];
    const float* a2b = (const float*)d_in[4];
    const float* Wih = (const float*)d_in[5];
    const float* Whh = (const float*)d_in[6];
    const float* bih = (const float*)d_in[7];
    const float* bhh = (const float*)d_in[8];
    ushort_t* ws = (ushort_t*)d_ws;

    hipLaunchKernelGGL(conv_kernel, dim3(CH_TOTAL / 256), dim3(256), 0, stream,
                       a1W, a2W, Wih, Whh, ws);
    hipLaunchKernelGGL(lstm_mfma, dim3(32), dim3(512), 0, stream,
                       X, a1b, a2b, bih, bhh, ws, (float*)d_out);
}

// Round 5
// 7473.060 us; speedup vs baseline: 1.4226x; 1.0009x over previous
//
#include <hip/hip_runtime.h>

// InputAttnEncoder round 5: round 4 + explicit __launch_bounds__(512, 2).
// Round 4's VGPR_Count=128 proved the compiler capped registers for 4 waves/SIMD
// and spilled w_ih/agate to scratch (the whole runtime). 8-wave block = 2 waves/SIMD
// -> legal cap is 256 VGPRs; declare it. Register audit ~240/256, no spill expected.

#define Bb 512
#define Tt 256
#define Ff 128
#define Hh 256

typedef unsigned short ushort_t;
typedef short s16x8 __attribute__((ext_vector_type(8)));
typedef float f32x4 __attribute__((ext_vector_type(4)));

#define A1_NK 20
#define A2_NK 9
#define IH_NK 4
#define HH_NK 8
#define CH_A1 0
#define CH_A2 21760
#define CH_IH 26368
#define CH_HH 42752
#define CH_TOTAL 75520

#define ZP 648    // z row pitch (ushort): [x 0..127 | h 128..383 | c 384..639]
#define AP 296    // attn score row pitch (K padded 257->288, pads zero)
#define XIP 136   // xi row pitch

__device__ inline ushort_t f2b(float f) {
    unsigned u = __float_as_uint(f);
    unsigned r = (u + 0x7fffu + ((u >> 16) & 1u)) >> 16;  // RNE
    return (ushort_t)r;
}
__device__ inline float b2f(ushort_t u) {
    return __uint_as_float(((unsigned)u) << 16);
}
__device__ inline float fast_sig(float x) { return 1.f / (1.f + __expf(-x)); }
__device__ inline float fast_tanh(float x) {
    float cx = fminf(fmaxf(x, -15.f), 15.f);
    float e = __expf(2.f * cx);
    return (e - 1.f) / (e + 1.f);
}

__global__ void conv_kernel(const float* __restrict__ a1,  // [257][640]
                            const float* __restrict__ a2,  // [128][257]
                            const float* __restrict__ ih,  // [1024][128]
                            const float* __restrict__ hh,  // [1024][256]
                            ushort_t* __restrict__ ws) {
    int idx = blockIdx.x * 256 + threadIdx.x;
    if (idx >= CH_TOTAL) return;
    int lane = idx & 63;
    int jo = lane & 15;
    int ko = (lane >> 4) * 8;
    float v[8];
    if (idx < CH_A2) {
        int cix = idx >> 6;
        int tile = cix / A1_NK, kc = cix % A1_NK;
        int j = tile * 16 + jo, k = kc * 32 + ko;
        #pragma unroll
        for (int e = 0; e < 8; ++e) v[e] = (j < 257) ? a1[j * 640 + k + e] : 0.f;
    } else if (idx < CH_IH) {
        int cix = (idx - CH_A2) >> 6;
        int tile = cix / A2_NK, kc = cix % A2_NK;
        int j = tile * 16 + jo, k = kc * 32 + ko;
        #pragma unroll
        for (int e = 0; e < 8; ++e) v[e] = (k + e < 257) ? a2[j * 257 + k + e] : 0.f;
    } else if (idx < CH_HH) {
        int cix = (idx - CH_IH) >> 6;
        int tile = cix / IH_NK, kc = cix % IH_NK;
        int j = tile * 16 + jo, k = kc * 32 + ko;
        #pragma unroll
        for (int e = 0; e < 8; ++e) v[e] = ih[j * 128 + k + e];
    } else {
        int cix = (idx - CH_HH) >> 6;
        int tile = cix / HH_NK, kc = cix % HH_NK;
        int j = tile * 16 + jo, k = kc * 32 + ko;
        #pragma unroll
        for (int e = 0; e < 8; ++e) v[e] = hh[j * 256 + k + e];
    }
    union { s16x8 v8; ushort_t u[8]; } o;
    #pragma unroll
    for (int e = 0; e < 8; ++e) o.u[e] = f2b(v[e]);
    ((s16x8*)ws)[idx] = o.v8;
}

__global__ __launch_bounds__(512, 2) void lstm_mfma(
    const float* __restrict__ X,    // [512][256][128]
    const float* __restrict__ b1,   // [257]
    const float* __restrict__ b2,   // [128]
    const float* __restrict__ bih,  // [1024]
    const float* __restrict__ bhh,  // [1024]
    const ushort_t* __restrict__ wsw,
    float* __restrict__ out)        // hs [512][256][256] then cs
{
    __shared__ s16x8    a2w[8 * A2_NK * 64];   // 73,728 B: attn2 weights pinned
    __shared__ ushort_t z_bf[16][ZP];          // 20,736 B
    __shared__ ushort_t a_bf[16][AP];          //  9,472 B
    __shared__ ushort_t xi_bf[16][XIP];        //  4,352 B

    const int tid = threadIdx.x;
    const int w   = tid >> 6;       // wave 0..7
    const int l   = tid & 63;
    const int lj  = l & 15;
    const int lr4 = (l >> 4) * 4;
    const int lk8 = (l >> 4) * 8;
    const int b0  = blockIdx.x * 16;

    const s16x8* __restrict__ W8 = (const s16x8*)wsw;

    // ---------------- pinned weights: Wih in VGPRs (32 chunks = 128 VGPR) ----------------
    s16x8 w_ih[32];
    float bgq[8];
    #pragma unroll
    for (int u = 0; u < 8; ++u) {
        int n = (u & 3) * 16 + (u >> 2) * 8 + w;   // gate tile
        #pragma unroll
        for (int kc = 0; kc < IH_NK; ++kc)
            w_ih[u * 4 + kc] = W8[CH_IH + (n * IH_NK + kc) * 64 + l];
        int j = n * 16 + lj;
        bgq[u] = bih[j] + bhh[j];
    }

    // ---------------- pinned weights: attn2 into LDS ----------------
    for (int i = tid; i < 8 * A2_NK * 64; i += 512) a2w[i] = W8[CH_A2 + i];

    // ---------------- biases ----------------
    float bA1_0 = b1[16 * w + lj];
    float bA1_1 = b1[128 + 16 * w + lj];
    float b1_256 = (w == 0) ? b1[256] : 0.f;
    float bA2 = b2[16 * w + lj];

    f32x4 agate[8];
    float c_reg[8];
    #pragma unroll
    for (int u = 0; u < 8; ++u) c_reg[u] = 0.f;

    // ---------------- LDS init ----------------
    {   // h,c = 0 (bf16): 16 rows x 512 = 1024 chunks of 8 ushorts
        s16x8 zz = {0, 0, 0, 0, 0, 0, 0, 0};
        #pragma unroll
        for (int rep = 0; rep < 2; ++rep) {
            int i = tid + rep * 512;
            int r = i >> 6, c = (i & 63) * 8;
            *(s16x8*)&z_bf[r][128 + c] = zz;
        }
        for (int i = tid; i < 592; i += 512) {   // a_bf incl pads
            int r = i / 37, c = (i - r * 37) * 8;
            *(s16x8*)&a_bf[r][c] = zz;
        }
    }
    if (tid < 256) {  // x_0
        int r = tid >> 4, c = (tid & 15) * 8;
        float4 x0 = *(const float4*)&X[((size_t)(b0 + r) * Tt) * Ff + c];
        float4 x1 = *(const float4*)&X[((size_t)(b0 + r) * Tt) * Ff + c + 4];
        s16x8 v;
        v[0] = (short)f2b(x0.x); v[1] = (short)f2b(x0.y);
        v[2] = (short)f2b(x0.z); v[3] = (short)f2b(x0.w);
        v[4] = (short)f2b(x1.x); v[5] = (short)f2b(x1.y);
        v[6] = (short)f2b(x1.z); v[7] = (short)f2b(x1.w);
        *(s16x8*)&z_bf[r][c] = v;
    }
    __syncthreads();

    float* __restrict__ hs = out;
    float* __restrict__ cs = out + (size_t)Bb * Tt * Hh;

    float4 xp0, xp1;

    for (int t = 0; t < Tt; ++t) {
        // ===== Phase A: attn1, streamed (tiles w and 8+w; wave 0 also tile 16) =====
        {
            const s16x8* Wa = W8 + CH_A1;
            s16x8 bufA[5][2];
            #pragma unroll
            for (int kc = 0; kc < 4; ++kc) {
                bufA[kc][0] = Wa[(w * A1_NK + kc) * 64 + l];
                bufA[kc][1] = Wa[((8 + w) * A1_NK + kc) * 64 + l];
            }
            f32x4 acc0 = {0.f, 0.f, 0.f, 0.f};
            f32x4 acc1 = {0.f, 0.f, 0.f, 0.f};
            #pragma unroll
            for (int kc = 0; kc < A1_NK; ++kc) {
                if (kc + 4 < A1_NK) {
                    bufA[(kc + 4) % 5][0] = Wa[(w * A1_NK + kc + 4) * 64 + l];
                    bufA[(kc + 4) % 5][1] = Wa[((8 + w) * A1_NK + kc + 4) * 64 + l];
                }
                s16x8 a = *(const s16x8*)&z_bf[lj][kc * 32 + lk8];
                acc0 = __builtin_amdgcn_mfma_f32_16x16x32_bf16(a, bufA[kc % 5][0], acc0, 0, 0, 0);
                acc1 = __builtin_amdgcn_mfma_f32_16x16x32_bf16(a, bufA[kc % 5][1], acc1, 0, 0, 0);
            }
            int j0 = 16 * w + lj;
            #pragma unroll
            for (int q = 0; q < 4; ++q) {
                a_bf[lr4 + q][j0]       = f2b(fast_tanh(acc0[q] + bA1_0));
                a_bf[lr4 + q][128 + j0] = f2b(fast_tanh(acc1[q] + bA1_1));
            }
        }
        if (w == 0) {  // attn1 tile 16 (only j=256 valid)
            const s16x8* Wa = W8 + CH_A1 + 16 * A1_NK * 64;
            s16x8 buf16[4];
            #pragma unroll
            for (int kc = 0; kc < 3; ++kc) buf16[kc] = Wa[kc * 64 + l];
            f32x4 acc2 = {0.f, 0.f, 0.f, 0.f};
            #pragma unroll
            for (int kc = 0; kc < A1_NK; ++kc) {
                if (kc + 3 < A1_NK) buf16[(kc + 3) & 3] = Wa[(kc + 3) * 64 + l];
                s16x8 a = *(const s16x8*)&z_bf[lj][kc * 32 + lk8];
                acc2 = __builtin_amdgcn_mfma_f32_16x16x32_bf16(a, buf16[kc & 3], acc2, 0, 0, 0);
            }
            if (lj == 0) {
                #pragma unroll
                for (int q = 0; q < 4; ++q)
                    a_bf[lr4 + q][256] = f2b(fast_tanh(acc2[q] + b1_256));
            }
        }
        __syncthreads();  // ---- a_bf ready ----

        // ===== Phase B: x prefetch + Whh (streamed) + attn2 (LDS) =====
        if (tid < 256 && t + 1 < Tt) {
            const float* xs = &X[((size_t)(b0 + (tid >> 4)) * Tt + (t + 1)) * Ff + (tid & 15) * 8];
            xp0 = *(const float4*)xs;
            xp1 = *(const float4*)(xs + 4);
        }
        {
            // Whh: kc outer (8), tiles inner (8, in halves of 4), dbuf by half-group
            s16x8 bufH[2][4];
            #pragma unroll
            for (int j2 = 0; j2 < 4; ++j2) {
                int n = (j2 & 3) * 16 + 0 * 8 + w;            // u = j2 (q=0,i=j2)
                bufH[0][j2] = W8[CH_HH + (n * HH_NK + 0) * 64 + l];
            }
            #pragma unroll
            for (int u = 0; u < 8; ++u)
                agate[u] = (f32x4){bgq[u], bgq[u], bgq[u], bgq[u]};

            // attn2 (LDS-pinned B) — runs while first Whh group is in flight
            {
                f32x4 acc = {0.f, 0.f, 0.f, 0.f};
                #pragma unroll
                for (int kc = 0; kc < A2_NK; ++kc) {
                    s16x8 a = *(const s16x8*)&a_bf[lj][kc * 32 + lk8];
                    s16x8 b = a2w[(w * A2_NK + kc) * 64 + l];
                    acc = __builtin_amdgcn_mfma_f32_16x16x32_bf16(a, b, acc, 0, 0, 0);
                }
                int j = 16 * w + lj;
                #pragma unroll
                for (int q = 0; q < 4; ++q) {
                    int r = lr4 + q;
                    float xi = (acc[q] + bA2) * b2f(z_bf[r][j]);
                    xi_bf[r][j] = f2b(xi);
                }
            }

            // Whh main: 16 groups of 4 chunks (g = kc*2 + half)
            s16x8 ah;
            #pragma unroll
            for (int g = 0; g < 16; ++g) {
                const int kc = g >> 1, half = g & 1;
                if (g + 1 < 16) {
                    const int kn = (g + 1) >> 1, hn = (g + 1) & 1;
                    #pragma unroll
                    for (int j2 = 0; j2 < 4; ++j2) {
                        int u = hn * 4 + j2;
                        int n = (u & 3) * 16 + (u >> 2) * 8 + w;
                        bufH[(g + 1) & 1][j2] = W8[CH_HH + (n * HH_NK + kn) * 64 + l];
                    }
                }
                if (half == 0)
                    ah = *(const s16x8*)&z_bf[lj][128 + kc * 32 + lk8];
                #pragma unroll
                for (int j2 = 0; j2 < 4; ++j2) {
                    int u = half * 4 + j2;
                    agate[u] = __builtin_amdgcn_mfma_f32_16x16x32_bf16(ah, bufH[g & 1][j2], agate[u], 0, 0, 0);
                }
            }
        }
        __syncthreads();  // ---- xi ready ----

        // ===== Phase C: Wih (pinned) + pointwise + state/output writes =====
        {
            #pragma unroll
            for (int kc = 0; kc < IH_NK; ++kc) {
                s16x8 a = *(const s16x8*)&xi_bf[lj][kc * 32 + lk8];
                #pragma unroll
                for (int u = 0; u < 8; ++u)
                    agate[u] = __builtin_amdgcn_mfma_f32_16x16x32_bf16(a, w_ih[u * 4 + kc], agate[u], 0, 0, 0);
            }
            #pragma unroll
            for (int q = 0; q < 2; ++q) {
                int d = 128 * q + 16 * w + lj;
                #pragma unroll
                for (int qq = 0; qq < 4; ++qq) {
                    int r = lr4 + qq;
                    float gi = agate[q * 4 + 0][qq];
                    float gf = agate[q * 4 + 1][qq];
                    float gg = agate[q * 4 + 2][qq];
                    float go = agate[q * 4 + 3][qq];
                    float ig = fast_sig(gi);
                    float fg = fast_sig(gf);
                    float g_g = fast_tanh(gg);
                    float og = fast_sig(go);
                    float cn = fmaf(fg, c_reg[q * 4 + qq], ig * g_g);
                    float hn = og * fast_tanh(cn);
                    c_reg[q * 4 + qq] = cn;
                    z_bf[r][128 + d] = f2b(hn);
                    z_bf[r][384 + d] = f2b(cn);
                    size_t oi = ((size_t)(b0 + r) * Tt + t) * Hh + d;
                    hs[oi] = hn;
                    cs[oi] = cn;
                }
            }
        }
        if (tid < 256 && t + 1 < Tt) {  // write x_{t+1}
            int r = tid >> 4, c = (tid & 15) * 8;
            s16x8 v;
            v[0] = (short)f2b(xp0.x); v[1] = (short)f2b(xp0.y);
            v[2] = (short)f2b(xp0.z); v[3] = (short)f2b(xp0.w);
            v[4] = (short)f2b(xp1.x); v[5] = (short)f2b(xp1.y);
            v[6] = (short)f2b(xp1.z); v[7] = (short)f2b(xp1.w);
            *(s16x8*)&z_bf[r][c] = v;
        }
        __syncthreads();  // ---- state for t+1 ready ----
    }
}

extern "C" void kernel_launch(void* const* d_in, const int* in_sizes, int n_in,
                              void* d_out, int out_size, void* d_ws, size_t ws_size,
                              hipStream_t stream) {
    const float* X   = (const float*)d_in[0];
    const float* a1W = (const float*)d_in[1];
    const float* a1b = (const float*)d_in[2];
    const float* a2W = (const float*)d_in[3];
    const float* a2b = (const float*)d_in[4];
    const float* Wih = (const float*)d_in[5];
    const float* Whh = (const float*)d_in[6];
    const float* bih = (const float*)d_in[7];
    const float* bhh = (const float*)d_in[8];
    ushort_t* ws = (ushort_t*)d_ws;

    hipLaunchKernelGGL(conv_kernel, dim3(CH_TOTAL / 256), dim3(256), 0, stream,
                       a1W, a2W, Wih, Whh, ws);
    hipLaunchKernelGGL(lstm_mfma, dim3(32), dim3(512), 0, stream,
                       X, a1b, a2b, bih, bhh, ws, (float*)d_out);
}

// Round 6
// 7441.722 us; speedup vs baseline: 1.4286x; 1.0042x over previous
//
#include <hip/hip_runtime.h>

// InputAttnEncoder round 6: remove w_ih VGPR pinning (the spill source).
// Rounds 4/5: VGPR_Count=128 cap vs ~240 demand -> agate/w_ih spilled to scratch,
// ~95 accumulate-MFMAs/step each round-tripping C through scratch = 29us/step.
// Fix: stream Wih from L2 like Whh (ring prefetch, prologue before the barrier).
// Peak live regs ~130 -> fits any cap. attn2 stays LDS-pinned. 3 matmul phases
// + pointwise, gates/c in registers, 32 blocks x 512 threads.

#define Bb 512
#define Tt 256
#define Ff 128
#define Hh 256

typedef unsigned short ushort_t;
typedef short s16x8 __attribute__((ext_vector_type(8)));
typedef float f32x4 __attribute__((ext_vector_type(4)));

#define A1_NK 20
#define A2_NK 9
#define IH_NK 4
#define HH_NK 8
#define CH_A1 0
#define CH_A2 21760
#define CH_IH 26368
#define CH_HH 42752
#define CH_TOTAL 75520

#define ZP 648    // z row pitch (ushort): [x 0..127 | h 128..383 | c 384..639]
#define AP 296    // attn score row pitch (K padded 257->288, pads zero)
#define XIP 136   // xi row pitch

__device__ inline ushort_t f2b(float f) {
    unsigned u = __float_as_uint(f);
    unsigned r = (u + 0x7fffu + ((u >> 16) & 1u)) >> 16;  // RNE
    return (ushort_t)r;
}
__device__ inline float b2f(ushort_t u) {
    return __uint_as_float(((unsigned)u) << 16);
}
__device__ inline float fast_sig(float x) { return 1.f / (1.f + __expf(-x)); }
__device__ inline float fast_tanh(float x) {
    float cx = fminf(fmaxf(x, -15.f), 15.f);
    float e = __expf(2.f * cx);
    return (e - 1.f) / (e + 1.f);
}

__global__ void conv_kernel(const float* __restrict__ a1,  // [257][640]
                            const float* __restrict__ a2,  // [128][257]
                            const float* __restrict__ ih,  // [1024][128]
                            const float* __restrict__ hh,  // [1024][256]
                            ushort_t* __restrict__ ws) {
    int idx = blockIdx.x * 256 + threadIdx.x;
    if (idx >= CH_TOTAL) return;
    int lane = idx & 63;
    int jo = lane & 15;
    int ko = (lane >> 4) * 8;
    float v[8];
    if (idx < CH_A2) {
        int cix = idx >> 6;
        int tile = cix / A1_NK, kc = cix % A1_NK;
        int j = tile * 16 + jo, k = kc * 32 + ko;
        #pragma unroll
        for (int e = 0; e < 8; ++e) v[e] = (j < 257) ? a1[j * 640 + k + e] : 0.f;
    } else if (idx < CH_IH) {
        int cix = (idx - CH_A2) >> 6;
        int tile = cix / A2_NK, kc = cix % A2_NK;
        int j = tile * 16 + jo, k = kc * 32 + ko;
        #pragma unroll
        for (int e = 0; e < 8; ++e) v[e] = (k + e < 257) ? a2[j * 257 + k + e] : 0.f;
    } else if (idx < CH_HH) {
        int cix = (idx - CH_IH) >> 6;
        int tile = cix / IH_NK, kc = cix % IH_NK;
        int j = tile * 16 + jo, k = kc * 32 + ko;
        #pragma unroll
        for (int e = 0; e < 8; ++e) v[e] = ih[j * 128 + k + e];
    } else {
        int cix = (idx - CH_HH) >> 6;
        int tile = cix / HH_NK, kc = cix % HH_NK;
        int j = tile * 16 + jo, k = kc * 32 + ko;
        #pragma unroll
        for (int e = 0; e < 8; ++e) v[e] = hh[j * 256 + k + e];
    }
    union { s16x8 v8; ushort_t u[8]; } o;
    #pragma unroll
    for (int e = 0; e < 8; ++e) o.u[e] = f2b(v[e]);
    ((s16x8*)ws)[idx] = o.v8;
}

__global__ __launch_bounds__(512, 1) void lstm_mfma(
    const float* __restrict__ X,    // [512][256][128]
    const float* __restrict__ b1,   // [257]
    const float* __restrict__ b2,   // [128]
    const float* __restrict__ bih,  // [1024]
    const float* __restrict__ bhh,  // [1024]
    const ushort_t* __restrict__ wsw,
    float* __restrict__ out)        // hs [512][256][256] then cs
{
    __shared__ s16x8    a2w[8 * A2_NK * 64];   // 73,728 B: attn2 weights pinned
    __shared__ ushort_t z_bf[16][ZP];          // 20,736 B
    __shared__ ushort_t a_bf[16][AP];          //  9,472 B
    __shared__ ushort_t xi_bf[16][XIP];        //  4,352 B

    const int tid = threadIdx.x;
    const int w   = tid >> 6;       // wave 0..7
    const int l   = tid & 63;
    const int lj  = l & 15;
    const int lr4 = (l >> 4) * 4;
    const int lk8 = (l >> 4) * 8;
    const int b0  = blockIdx.x * 16;

    const s16x8* __restrict__ W8 = (const s16x8*)wsw;

    // ---------------- gate biases ----------------
    float bgq[8];
    #pragma unroll
    for (int u = 0; u < 8; ++u) {
        int n = (u & 3) * 16 + (u >> 2) * 8 + w;   // gate tile
        int j = n * 16 + lj;
        bgq[u] = bih[j] + bhh[j];
    }

    // ---------------- pinned weights: attn2 into LDS ----------------
    for (int i = tid; i < 8 * A2_NK * 64; i += 512) a2w[i] = W8[CH_A2 + i];

    // ---------------- biases ----------------
    float bA1_0 = b1[16 * w + lj];
    float bA1_1 = b1[128 + 16 * w + lj];
    float b1_256 = (w == 0) ? b1[256] : 0.f;
    float bA2 = b2[16 * w + lj];

    f32x4 agate[8];
    float c_reg[8];
    #pragma unroll
    for (int u = 0; u < 8; ++u) c_reg[u] = 0.f;

    // ---------------- LDS init ----------------
    {   // h,c = 0 (bf16): 16 rows x 512 = 1024 chunks of 8 ushorts
        s16x8 zz = {0, 0, 0, 0, 0, 0, 0, 0};
        #pragma unroll
        for (int rep = 0; rep < 2; ++rep) {
            int i = tid + rep * 512;
            int r = i >> 6, c = (i & 63) * 8;
            *(s16x8*)&z_bf[r][128 + c] = zz;
        }
        for (int i = tid; i < 592; i += 512) {   // a_bf incl pads
            int r = i / 37, c = (i - r * 37) * 8;
            *(s16x8*)&a_bf[r][c] = zz;
        }
    }
    if (tid < 256) {  // x_0
        int r = tid >> 4, c = (tid & 15) * 8;
        float4 x0 = *(const float4*)&X[((size_t)(b0 + r) * Tt) * Ff + c];
        float4 x1 = *(const float4*)&X[((size_t)(b0 + r) * Tt) * Ff + c + 4];
        s16x8 v;
        v[0] = (short)f2b(x0.x); v[1] = (short)f2b(x0.y);
        v[2] = (short)f2b(x0.z); v[3] = (short)f2b(x0.w);
        v[4] = (short)f2b(x1.x); v[5] = (short)f2b(x1.y);
        v[6] = (short)f2b(x1.z); v[7] = (short)f2b(x1.w);
        *(s16x8*)&z_bf[r][c] = v;
    }
    __syncthreads();

    float* __restrict__ hs = out;
    float* __restrict__ cs = out + (size_t)Bb * Tt * Hh;

    float4 xp0, xp1;

    for (int t = 0; t < Tt; ++t) {
        // ===== Phase A: attn1, streamed (tiles w and 8+w; wave 0 also tile 16) =====
        {
            const s16x8* Wa = W8 + CH_A1;
            s16x8 bufA[5][2];
            #pragma unroll
            for (int kc = 0; kc < 4; ++kc) {
                bufA[kc][0] = Wa[(w * A1_NK + kc) * 64 + l];
                bufA[kc][1] = Wa[((8 + w) * A1_NK + kc) * 64 + l];
            }
            f32x4 acc0 = {0.f, 0.f, 0.f, 0.f};
            f32x4 acc1 = {0.f, 0.f, 0.f, 0.f};
            #pragma unroll
            for (int kc = 0; kc < A1_NK; ++kc) {
                if (kc + 4 < A1_NK) {
                    bufA[(kc + 4) % 5][0] = Wa[(w * A1_NK + kc + 4) * 64 + l];
                    bufA[(kc + 4) % 5][1] = Wa[((8 + w) * A1_NK + kc + 4) * 64 + l];
                }
                s16x8 a = *(const s16x8*)&z_bf[lj][kc * 32 + lk8];
                acc0 = __builtin_amdgcn_mfma_f32_16x16x32_bf16(a, bufA[kc % 5][0], acc0, 0, 0, 0);
                acc1 = __builtin_amdgcn_mfma_f32_16x16x32_bf16(a, bufA[kc % 5][1], acc1, 0, 0, 0);
            }
            int j0 = 16 * w + lj;
            #pragma unroll
            for (int q = 0; q < 4; ++q) {
                a_bf[lr4 + q][j0]       = f2b(fast_tanh(acc0[q] + bA1_0));
                a_bf[lr4 + q][128 + j0] = f2b(fast_tanh(acc1[q] + bA1_1));
            }
        }
        if (w == 0) {  // attn1 tile 16 (only j=256 valid)
            const s16x8* Wa = W8 + CH_A1 + 16 * A1_NK * 64;
            s16x8 buf16[4];
            #pragma unroll
            for (int kc = 0; kc < 3; ++kc) buf16[kc] = Wa[kc * 64 + l];
            f32x4 acc2 = {0.f, 0.f, 0.f, 0.f};
            #pragma unroll
            for (int kc = 0; kc < A1_NK; ++kc) {
                if (kc + 3 < A1_NK) buf16[(kc + 3) & 3] = Wa[(kc + 3) * 64 + l];
                s16x8 a = *(const s16x8*)&z_bf[lj][kc * 32 + lk8];
                acc2 = __builtin_amdgcn_mfma_f32_16x16x32_bf16(a, buf16[kc & 3], acc2, 0, 0, 0);
            }
            if (lj == 0) {
                #pragma unroll
                for (int q = 0; q < 4; ++q)
                    a_bf[lr4 + q][256] = f2b(fast_tanh(acc2[q] + b1_256));
            }
        }
        __syncthreads();  // ---- a_bf ready ----

        // ===== Phase B: x prefetch + Whh (streamed) + attn2 (LDS) =====
        if (tid < 256 && t + 1 < Tt) {
            const float* xs = &X[((size_t)(b0 + (tid >> 4)) * Tt + (t + 1)) * Ff + (tid & 15) * 8];
            xp0 = *(const float4*)xs;
            xp1 = *(const float4*)(xs + 4);
        }
        {
            // Whh: kc outer (8), tiles inner (8, in halves of 4), dbuf by half-group
            s16x8 bufH[2][4];
            #pragma unroll
            for (int j2 = 0; j2 < 4; ++j2) {
                int n = (j2 & 3) * 16 + 0 * 8 + w;            // u = j2 (q=0,i=j2)
                bufH[0][j2] = W8[CH_HH + (n * HH_NK + 0) * 64 + l];
            }
            #pragma unroll
            for (int u = 0; u < 8; ++u)
                agate[u] = (f32x4){bgq[u], bgq[u], bgq[u], bgq[u]};

            // attn2 (LDS-pinned B) — runs while first Whh group is in flight
            {
                f32x4 acc = {0.f, 0.f, 0.f, 0.f};
                #pragma unroll
                for (int kc = 0; kc < A2_NK; ++kc) {
                    s16x8 a = *(const s16x8*)&a_bf[lj][kc * 32 + lk8];
                    s16x8 b = a2w[(w * A2_NK + kc) * 64 + l];
                    acc = __builtin_amdgcn_mfma_f32_16x16x32_bf16(a, b, acc, 0, 0, 0);
                }
                int j = 16 * w + lj;
                #pragma unroll
                for (int q = 0; q < 4; ++q) {
                    int r = lr4 + q;
                    float xi = (acc[q] + bA2) * b2f(z_bf[r][j]);
                    xi_bf[r][j] = f2b(xi);
                }
            }

            // Whh main: 16 groups of 4 chunks (g = kc*2 + half)
            s16x8 ah;
            #pragma unroll
            for (int g = 0; g < 16; ++g) {
                const int kc = g >> 1, half = g & 1;
                if (g + 1 < 16) {
                    const int kn = (g + 1) >> 1, hn = (g + 1) & 1;
                    #pragma unroll
                    for (int j2 = 0; j2 < 4; ++j2) {
                        int u = hn * 4 + j2;
                        int n = (u & 3) * 16 + (u >> 2) * 8 + w;
                        bufH[(g + 1) & 1][j2] = W8[CH_HH + (n * HH_NK + kn) * 64 + l];
                    }
                }
                if (half == 0)
                    ah = *(const s16x8*)&z_bf[lj][128 + kc * 32 + lk8];
                #pragma unroll
                for (int j2 = 0; j2 < 4; ++j2) {
                    int u = half * 4 + j2;
                    agate[u] = __builtin_amdgcn_mfma_f32_16x16x32_bf16(ah, bufH[g & 1][j2], agate[u], 0, 0, 0);
                }
            }
        }

        // Wih group-0 prologue: issue BEFORE the barrier so latency hides under it
        s16x8 bufI[2][4];
        #pragma unroll
        for (int j2 = 0; j2 < 4; ++j2) {
            int n = (j2 & 3) * 16 + 0 * 8 + w;                // u = j2 (kc=0, half=0)
            bufI[0][j2] = W8[CH_IH + (n * IH_NK + 0) * 64 + l];
        }
        __syncthreads();  // ---- xi ready ----

        // ===== Phase C: Wih (streamed) + pointwise + state/output writes =====
        {
            // 8 groups of 4 chunks (g = kc*2 + half), ring-of-2 prefetch
            s16x8 ax;
            #pragma unroll
            for (int g = 0; g < 8; ++g) {
                const int kc = g >> 1, half = g & 1;
                if (g + 1 < 8) {
                    const int kn = (g + 1) >> 1, hn = (g + 1) & 1;
                    #pragma unroll
                    for (int j2 = 0; j2 < 4; ++j2) {
                        int u = hn * 4 + j2;
                        int n = (u & 3) * 16 + (u >> 2) * 8 + w;
                        bufI[(g + 1) & 1][j2] = W8[CH_IH + (n * IH_NK + kn) * 64 + l];
                    }
                }
                if (half == 0)
                    ax = *(const s16x8*)&xi_bf[lj][kc * 32 + lk8];
                #pragma unroll
                for (int j2 = 0; j2 < 4; ++j2) {
                    int u = half * 4 + j2;
                    agate[u] = __builtin_amdgcn_mfma_f32_16x16x32_bf16(ax, bufI[g & 1][j2], agate[u], 0, 0, 0);
                }
            }
            #pragma unroll
            for (int q = 0; q < 2; ++q) {
                int d = 128 * q + 16 * w + lj;
                #pragma unroll
                for (int qq = 0; qq < 4; ++qq) {
                    int r = lr4 + qq;
                    float gi = agate[q * 4 + 0][qq];
                    float gf = agate[q * 4 + 1][qq];
                    float gg = agate[q * 4 + 2][qq];
                    float go = agate[q * 4 + 3][qq];
                    float ig = fast_sig(gi);
                    float fg = fast_sig(gf);
                    float g_g = fast_tanh(gg);
                    float og = fast_sig(go);
                    float cn = fmaf(fg, c_reg[q * 4 + qq], ig * g_g);
                    float hn = og * fast_tanh(cn);
                    c_reg[q * 4 + qq] = cn;
                    z_bf[r][128 + d] = f2b(hn);
                    z_bf[r][384 + d] = f2b(cn);
                    size_t oi = ((size_t)(b0 + r) * Tt + t) * Hh + d;
                    hs[oi] = hn;
                    cs[oi] = cn;
                }
            }
        }
        if (tid < 256 && t + 1 < Tt) {  // write x_{t+1}
            int r = tid >> 4, c = (tid & 15) * 8;
            s16x8 v;
            v[0] = (short)f2b(xp0.x); v[1] = (short)f2b(xp0.y);
            v[2] = (short)f2b(xp0.z); v[3] = (short)f2b(xp0.w);
            v[4] = (short)f2b(xp1.x); v[5] = (short)f2b(xp1.y);
            v[6] = (short)f2b(xp1.z); v[7] = (short)f2b(xp1.w);
            *(s16x8*)&z_bf[r][c] = v;
        }
        __syncthreads();  // ---- state for t+1 ready ----
    }
}

extern "C" void kernel_launch(void* const* d_in, const int* in_sizes, int n_in,
                              void* d_out, int out_size, void* d_ws, size_t ws_size,
                              hipStream_t stream) {
    const float* X   = (const float*)d_in[0];
    const float* a1W = (const float*)d_in[1];
    const float* a1b = (const float*)d_in[2];
    const float* a2W = (const float*)d_in[3];
    const float* a2b = (const float*)d_in[4];
    const float* Wih = (const float*)d_in[5];
    const float* Whh = (const float*)d_in[6];
    const float* bih = (const float*)d_in[7];
    const float* bhh = (const float*)d_in[8];
    ushort_t* ws = (ushort_t*)d_ws;

    hipLaunchKernelGGL(conv_kernel, dim3(CH_TOTAL / 256), dim3(256), 0, stream,
                       a1W, a2W, Wih, Whh, ws);
    hipLaunchKernelGGL(lstm_mfma, dim3(32), dim3(512), 0, stream,
                       X, a1b, a2b, bih, bhh, ws, (float*)d_out);
}